// Round 5
// baseline (132.715 us; speedup 1.0000x reference)
//
#include <hip/hip_runtime.h>
#include <hip/hip_fp16.h>

// CBOWSubword: out[t,:] = W[seq[t],:] + W[pre[t],:] + W[post[t],:]
// B*S = 131072 tokens, D = 128 fp32.
//
// R5 (= R3 + compile fixes): gather is random-access-efficiency bound
// (~3.8 TB/s vs 6.3 streaming; R2 showed MLP is not the limiter). Halve
// the random bytes: pass 1 converts the fp32 table to fp16 in d_ws
// (streaming, full BW), pass 2 gathers 256-B fp16 rows, sums in fp32,
// writes fp32 out. fp16 abs err ~0.01 << 0.19125 threshold.
// Notes: nontemporal builtins need ext_vector_type (not HIP float4);
// ext-vector elements can't have their address taken -> bit_cast copies.

#define D4 32  // float4 per fp32 row; also uint2 per fp16 row

typedef float    v4f __attribute__((ext_vector_type(4)));
typedef unsigned v2u __attribute__((ext_vector_type(2)));

__device__ inline float2 h2_to_f2(unsigned u) {
    __half2 h = __builtin_bit_cast(__half2, u);
    return __half22float2(h);
}

// ---- pass 1: fp32 -> fp16 table conversion (1 float4 per thread) ----
__global__ __launch_bounds__(256) void convert_f32_to_f16_kernel(
    const v4f* __restrict__ w, v2u* __restrict__ o, int n4)
{
    int i = blockIdx.x * blockDim.x + threadIdx.x;
    if (i >= n4) return;
    v4f v = __builtin_nontemporal_load(&w[i]);  // fp32 table not reused
    __half2 h0 = __floats2half2_rn(v.x, v.y);
    __half2 h1 = __floats2half2_rn(v.z, v.w);
    v2u p;
    p.x = __builtin_bit_cast(unsigned, h0);
    p.y = __builtin_bit_cast(unsigned, h1);
    o[i] = p;
}

// ---- pass 2: gather 3 fp16 rows, sum fp32, store fp32 ----
__global__ __launch_bounds__(256) void cbow_gather3_f16_kernel(
    const int* __restrict__ seq,
    const int* __restrict__ pre,
    const int* __restrict__ post,
    const v2u* __restrict__ wh,   // fp16 table: 32 x 8B per row
    v4f* __restrict__ out,
    int n_tokens)
{
    int tid   = blockIdx.x * blockDim.x + threadIdx.x;
    int token = tid >> 5;           // 32 lanes per token
    int lane  = tid & 31;           // 8 B of the 256-B fp16 row
    if (token >= n_tokens) return;

    int s = seq[token];
    int p = pre[token];
    int q = post[token];

    v2u ua = wh[(size_t)s * D4 + lane];
    v2u ub = wh[(size_t)p * D4 + lane];
    v2u uc = wh[(size_t)q * D4 + lane];

    float2 a0 = h2_to_f2(ua.x), a1 = h2_to_f2(ua.y);
    float2 b0 = h2_to_f2(ub.x), b1 = h2_to_f2(ub.y);
    float2 c0 = h2_to_f2(uc.x), c1 = h2_to_f2(uc.y);

    v4f r;
    r.x = a0.x + b0.x + c0.x;
    r.y = a0.y + b0.y + c0.y;
    r.z = a1.x + b1.x + c1.x;
    r.w = a1.y + b1.y + c1.y;

    out[(size_t)token * D4 + lane] = r;
}

// ---- fallback: fp32 gather (R1) if ws too small ----
__global__ __launch_bounds__(256) void cbow_gather3_f32_kernel(
    const int* __restrict__ seq,
    const int* __restrict__ pre,
    const int* __restrict__ post,
    const v4f* __restrict__ weight,
    v4f* __restrict__ out,
    int n_tokens)
{
    int tid   = blockIdx.x * blockDim.x + threadIdx.x;
    int token = tid >> 5;
    int lane  = tid & 31;
    if (token >= n_tokens) return;

    int s = seq[token];
    int p = pre[token];
    int q = post[token];

    v4f a = weight[(size_t)s * D4 + lane];
    v4f b = weight[(size_t)p * D4 + lane];
    v4f c = weight[(size_t)q * D4 + lane];

    out[(size_t)token * D4 + lane] = a + b + c;
}

extern "C" void kernel_launch(void* const* d_in, const int* in_sizes, int n_in,
                              void* d_out, int out_size, void* d_ws, size_t ws_size,
                              hipStream_t stream)
{
    const int*   seq  = (const int*)d_in[0];
    const int*   pre  = (const int*)d_in[1];
    const int*   post = (const int*)d_in[2];
    const float* w    = (const float*)d_in[3];

    const int n_tokens = in_sizes[0];           // 128*1024 = 131072
    const int w_elems  = in_sizes[3];           // VOCAB*128 = 12.8M
    const size_t need  = (size_t)w_elems * sizeof(__half);

    const int block = 256;
    const long total_threads = (long)n_tokens * 32;
    const int grid_g = (int)((total_threads + block - 1) / block);

    if (ws_size >= need) {
        // pass 1: convert table to fp16 in d_ws
        const int n4 = w_elems / 4;
        const int grid_c = (n4 + block - 1) / block;
        convert_f32_to_f16_kernel<<<grid_c, block, 0, stream>>>(
            (const v4f*)w, (v2u*)d_ws, n4);
        // pass 2: fp16 gather
        cbow_gather3_f16_kernel<<<grid_g, block, 0, stream>>>(
            seq, pre, post, (const v2u*)d_ws, (v4f*)d_out, n_tokens);
    } else {
        cbow_gather3_f32_kernel<<<grid_g, block, 0, stream>>>(
            seq, pre, post, (const v4f*)w, (v4f*)d_out, n_tokens);
    }
}

// Round 6
// 132.072 us; speedup vs baseline: 1.0049x; 1.0049x over previous
//
#include <hip/hip_runtime.h>

// CBOWSubword: out[t,:] = W[seq[t],:] + W[pre[t],:] + W[post[t],:]
// B*S = 131072 tokens, D = 128 fp32 (512 B per row).
//
// R6: fp32 single pass (R5's fp16 two-pass lost: 77 MB conversion stream
// >= random-fetch savings). Mapping change: ONE WAVE (64 lanes) per token,
// float2 per lane -> each gather instruction is exactly one contiguous
// 512-B row (best DRAM burst shape). 2 tokens per wave for idx-load ILP.
// Index loads are wave-uniform (tid>>6) -> scalarizable. nt stores keep
// the output stream from displacing table lines.

#define D2 64   // float2 per 128-float row
#define TPW 2   // tokens per wave

typedef float v2f __attribute__((ext_vector_type(2)));

__global__ __launch_bounds__(256) void cbow_gather3_wave_kernel(
    const int* __restrict__ seq,
    const int* __restrict__ pre,
    const int* __restrict__ post,
    const v2f* __restrict__ weight,
    v2f* __restrict__ out,
    int n_tokens, int chunk)
{
    int tid  = blockIdx.x * blockDim.x + threadIdx.x;
    int lane = tid & 63;        // float2 slot within the 512-B row
    int slot = tid >> 6;        // wave id = token slot in first chunk
    if (slot >= chunk) return;

    int  tok[TPW];
    bool val[TPW];
#pragma unroll
    for (int k = 0; k < TPW; ++k) {
        tok[k] = slot + k * chunk;
        val[k] = tok[k] < n_tokens;
    }

    // Phase 1: all index loads in flight (wave-uniform addresses).
    int is[TPW], ip[TPW], iq[TPW];
#pragma unroll
    for (int k = 0; k < TPW; ++k) {
        if (val[k]) {
            is[k] = seq[tok[k]];
            ip[k] = pre[tok[k]];
            iq[k] = post[tok[k]];
        } else {
            is[k] = ip[k] = iq[k] = 0;
        }
    }

    // Phase 2: all row gathers in flight; each instr = one 512-B row.
    v2f a[TPW], b[TPW], c[TPW];
#pragma unroll
    for (int k = 0; k < TPW; ++k) {
        a[k] = weight[(size_t)is[k] * D2 + lane];
        b[k] = weight[(size_t)ip[k] * D2 + lane];
        c[k] = weight[(size_t)iq[k] * D2 + lane];
    }

    // Phase 3: sum + nontemporal store.
#pragma unroll
    for (int k = 0; k < TPW; ++k) {
        if (val[k]) {
            v2f r = a[k] + b[k] + c[k];
            __builtin_nontemporal_store(r, &out[(size_t)tok[k] * D2 + lane]);
        }
    }
}

extern "C" void kernel_launch(void* const* d_in, const int* in_sizes, int n_in,
                              void* d_out, int out_size, void* d_ws, size_t ws_size,
                              hipStream_t stream)
{
    const int* seq    = (const int*)d_in[0];
    const int* pre    = (const int*)d_in[1];
    const int* post   = (const int*)d_in[2];
    const v2f* weight = (const v2f*)d_in[3];
    v2f*       out    = (v2f*)d_out;

    const int n_tokens = in_sizes[0];               // 131072
    const int chunk = (n_tokens + TPW - 1) / TPW;   // waves needed
    const long total_threads = (long)chunk * 64;
    const int block = 256;
    const int grid = (int)((total_threads + block - 1) / block);

    cbow_gather3_wave_kernel<<<grid, block, 0, stream>>>(
        seq, pre, post, weight, out, n_tokens, chunk);
}